// Round 8
// baseline (93.219 us; speedup 1.0000x reference)
//
#include <hip/hip_runtime.h>

#define SDIM 256
#define NSEQ 256
#define CDIM 32
#define CZ 128
#define IB 4
#define JB 4

typedef __bf16 bfx8 __attribute__((ext_vector_type(8)));
typedef float fx4 __attribute__((ext_vector_type(4)));
typedef float f32x16 __attribute__((ext_vector_type(16)));
typedef unsigned int u32x4 __attribute__((ext_vector_type(4)));

__device__ __forceinline__ unsigned short f2bf(float f) {
  unsigned int u = __float_as_uint(f);
  u += 0x7fffu + ((u >> 16) & 1u);
  return (unsigned short)(u >> 16);
}

__device__ __forceinline__ unsigned int cvtpk(float lo, float hi) {
  unsigned int r;
  asm("v_cvt_pk_bf16_f32 %0, %1, %2" : "=v"(r) : "v"(lo), "v"(hi));
  return r;
}

__device__ __forceinline__ void gload16(const void* g, void* l) {
  __builtin_amdgcn_global_load_lds((const __attribute__((address_space(1))) unsigned int*)g,
                                   (__attribute__((address_space(3))) unsigned int*)l,
                                   16, 0, 0);
}

// sigma(d,c): k' = e(c0,c1,c3) + 8*sl, sl = d + 32*c2 + 64*c4  (c2 = MFMA h-bit)

// ---------------- prep ----------------
// blocks [0,512): LN + half of ab-projection (dph: 0->a, 1->b), per s
// blocks [512,544): W_out -> w2T repack (4 z-rows each), 16x16x32-fragment-linear
__global__ __launch_bounds__(256) void opm_prep(
    const float* __restrict__ m_si, const float* __restrict__ gamma, const float* __restrict__ beta,
    const float* __restrict__ Wab, const float* __restrict__ Wout,
    unsigned short* __restrict__ a_t, unsigned short* __restrict__ b_t,
    unsigned short* __restrict__ w2T)
{
  __shared__ __align__(16) char shbuf[41216];
  const int b = blockIdx.x;
  const int t = threadIdx.x;
  if (b < 2 * SDIM) {
    float* xin = (float*)shbuf;                      // f32 [256][36] (padded)
    unsigned short* xt = (unsigned short*)shbuf;     // later: bf16 [32][256]
    fx4* wab4 = (fx4*)(shbuf + 36864);               // [32][8]
    float* gbuf = (float*)(shbuf + 36864 + 4096);    // [64]
    const int s = b >> 1, dph = b & 1;

    const float* msrc = m_si + s * 8192;
#pragma unroll
    for (int k = 0; k < 8; ++k) {
      const int q = t + k * 256;
      ((fx4*)xin)[(q >> 3) * 9 + (q & 7)] = ((const fx4*)msrc)[q];
    }
    wab4[t & 255] = ((const fx4*)(Wab + dph * 1024))[t & 255];
    if (t < 32) { gbuf[t] = gamma[t]; gbuf[32 + t] = beta[t]; }
    __syncthreads();

    float x[CDIM];
#pragma unroll
    for (int c = 0; c < CDIM; ++c) x[c] = xin[t * 36 + c];
    __syncthreads();   // xin reads done; shbuf reusable as xt

    float mu = 0.f;
#pragma unroll
    for (int c = 0; c < CDIM; ++c) mu += x[c];
    mu *= (1.f / CDIM);
    float var = 0.f;
#pragma unroll
    for (int c = 0; c < CDIM; ++c) { float d = x[c] - mu; var += d * d; }
    var *= (1.f / CDIM);
    const float inv = rsqrtf(var + 1e-5f);
    fx4 xv[8];
#pragma unroll
    for (int cq = 0; cq < 8; ++cq) {
      fx4 v;
#pragma unroll
      for (int j = 0; j < 4; ++j) {
        const int c = cq * 4 + j;
        v[j] = (x[c] - mu) * inv * gbuf[c] + gbuf[32 + c];
      }
      xv[cq] = v;
    }

    for (int dp = 0; dp < 32; ++dp) {
      fx4 a = xv[0] * wab4[dp * 8];
#pragma unroll
      for (int cq = 1; cq < 8; ++cq) a += xv[cq] * wab4[dp * 8 + cq];
      xt[dp * 256 + t] = f2bf(a[0] + a[1] + a[2] + a[3]);
    }
    __syncthreads();

    unsigned short* outb = dph ? b_t : a_t;
#pragma unroll
    for (int k = 0; k < 4; ++k) {
      const int q = t + k * 256;          // 16B chunks
      const int row = q >> 5, cc = q & 31;
      *(u32x4*)(outb + (s * 32 + row) * 256 + cc * 8) = *(const u32x4*)(shbuf + row * 512 + cc * 16);
    }
  } else {
    // repack to w2T16: elem (z, k') at ((z>>4)*32 + k'/32)*512 + ((k'>>3)&3)*128 + (z&15)*8 + (k'&7)
    unsigned short* lin = (unsigned short*)shbuf;    // 8 KB
    const int blk = b - 2 * SDIM;                    // 0..31
    const float* wsrc = Wout + blk * 4096;
#pragma unroll
    for (int jj = 0; jj < 4; ++jj) {
      const int q = t + jj * 256;                    // fx4 id
      const fx4 v = ((const fx4*)wsrc)[q];
      unsigned short* dst = lin + q * 4;
      dst[0] = f2bf(v[0]); dst[1] = f2bf(v[1]); dst[2] = f2bf(v[2]); dst[3] = f2bf(v[3]);
    }
    __syncthreads();
    const int z0 = blk * 4;
#pragma unroll
    for (int w = 0; w < 2; ++w) {
      const int id = t + w * 256;        // 0..511
      const int lz = id & 3;
      const int rest = id >> 2;          // 0..127
      const int g = rest & 3;
      const int ksg = rest >> 2;         // 0..31
      const int z = z0 + lz;
      unsigned short vals[8];
#pragma unroll
      for (int e = 0; e < 8; ++e) {
        const int kp = ksg * 32 + g * 8 + e;
        const int c = (kp & 3) | (((kp >> 8) & 1) << 2) | (((kp >> 2) & 1) << 3) | (((kp >> 9) & 1) << 4);
        const int d = (kp >> 3) & 31;
        vals[e] = lin[lz * 1024 + c * CDIM + d];
      }
      const int dest = ((z >> 4) * 32 + ksg) * 512 + g * 128 + (z & 15) * 8;
      *(u32x4*)(w2T + dest) = *(const u32x4*)vals;
    }
  }
}

// ---------------- main: 4x4 (i,j) tiles = 16 pairs/block, 256 threads, 32 KB LDS ----------------
// phase A: 4 waves x (64x64) wave-tile, 32x32x16 MFMA, double-buffered K=32 staging
// phase B: 16x16x32 MFMA, waves = (z-half 64) x (k-half 512); 1 O-read feeds 4 MFMAs
__global__ __launch_bounds__(256, 4) void opm_main(
    const unsigned short* __restrict__ a_t, const unsigned short* __restrict__ b_t,
    const unsigned short* __restrict__ w2T, const float* __restrict__ bout,
    float* __restrict__ out)
{
  // staging: A0 [0,8K) A1 [8K,16K) B0 [16K,24K) B1 [24K,32K)
  // O (after final phase-A barrier) overlays [0,32K); phase-B partials overlay [0,8K) after O reads
  __shared__ __align__(16) char smem[32768];
  char* o_sh = smem;

  const int tid = threadIdx.x;
  const int lane = tid & 63;
  const int wid = tid >> 6;           // 0..3
  const int l31 = lane & 31;
  const int h = lane >> 5;

  // 2-D XCD blocking: each XCD owns 32 i-tiles x 16 j-tiles (2MB a + 1MB b + 0.25MB W2 < 4MB L2)
  const int bxr = blockIdx.x;
  const int xc = bxr & 7;
  const int q9 = bxr >> 3;            // 0..511
  const int it = (xc & 1) * 32 + (q9 >> 4);
  const int jt = (xc >> 1) * 16 + (q9 & 15);
  const int i0 = it * IB;
  const int j0 = jt * JB;

  const int wm = wid >> 1;            // 0..1: M 64-row group
  const int wn = wid & 1;             // 0..1: N 64-row group
  const int wbase = wid * 1024;       // wave-uniform LDS staging offset unit

  f32x16 acc00 = {}, acc01 = {}, acc10 = {}, acc11 = {};

  // chunk q (16B) at offset q*16 holds global n-group gs = (q&3) ^ ((q>>3)&3)
  auto STAGE = [&](int buf, int nc) {
    const int nbase = nc * 32;
    char* A = smem + buf * 8192;
    char* B = smem + 16384 + buf * 8192;
#pragma unroll
    for (int pass = 0; pass < 2; ++pass) {
      const int q = pass * 256 + tid;
      const int row = q >> 2;
      const int gs = (q & 3) ^ ((q >> 3) & 3);
      const unsigned short* src = a_t + (i0 * 32 + row) * 256 + nbase + gs * 8;
      gload16(src, A + pass * 4096 + wbase);
    }
#pragma unroll
    for (int pass = 0; pass < 2; ++pass) {
      const int q = pass * 256 + tid;
      const int row = q >> 2;
      const int gs = (q & 3) ^ ((q >> 3) & 3);
      const unsigned short* src = b_t + (j0 * 32 + row) * 256 + nbase + gs * 8;
      gload16(src, B + pass * 4096 + wbase);
    }
  };

  auto COMPUTE = [&](int buf) {
    char* A = smem + buf * 8192;
    char* B = smem + 16384 + buf * 8192;
#pragma unroll
    for (int ks = 0; ks < 2; ++ks) {
      const int s = ks * 2 + h;
      bfx8 af0, af1, bf0, bf1;
      { const int r = wm * 64 + l31;      af0 = *(const bfx8*)(A + r * 64 + (((s ^ (r >> 1)) & 3) << 4)); }
      { const int r = wm * 64 + 32 + l31; af1 = *(const bfx8*)(A + r * 64 + (((s ^ (r >> 1)) & 3) << 4)); }
      { const int r = wn * 64 + l31;      bf0 = *(const bfx8*)(B + r * 64 + (((s ^ (r >> 1)) & 3) << 4)); }
      { const int r = wn * 64 + 32 + l31; bf1 = *(const bfx8*)(B + r * 64 + (((s ^ (r >> 1)) & 3) << 4)); }
      __builtin_amdgcn_s_setprio(1);
      acc00 = __builtin_amdgcn_mfma_f32_32x32x16_bf16(af0, bf0, acc00, 0, 0, 0);
      acc01 = __builtin_amdgcn_mfma_f32_32x32x16_bf16(af0, bf1, acc01, 0, 0, 0);
      acc10 = __builtin_amdgcn_mfma_f32_32x32x16_bf16(af1, bf0, acc10, 0, 0, 0);
      acc11 = __builtin_amdgcn_mfma_f32_32x32x16_bf16(af1, bf1, acc11, 0, 0, 0);
      __builtin_amdgcn_s_setprio(0);
    }
  };

  STAGE(0, 0);
#pragma unroll 2
  for (int t = 0; t < 8; ++t) {
    if (t < 7) {
      STAGE((t + 1) & 1, t + 1);
      asm volatile("s_waitcnt vmcnt(4)" ::: "memory");   // current chunk (4 loads/thread) landed
    } else {
      asm volatile("s_waitcnt vmcnt(0)" ::: "memory");
    }
    __builtin_amdgcn_s_barrier();
    asm volatile("" ::: "memory");
    COMPUTE(t & 1);
    asm volatile("s_waitcnt lgkmcnt(0)" ::: "memory");
    __builtin_amdgcn_s_barrier();
  }

  // ---- O -> LDS: pair p at [p*2048 + ((d + 32*c2 + 64*c4) ^ (p&7))*16]
  {
    const f32x16 av[4] = { acc00 * 0.00390625f, acc01 * 0.00390625f,
                           acc10 * 0.00390625f, acc11 * 0.00390625f };
#pragma unroll
    for (int mi = 0; mi < 2; ++mi) {
#pragma unroll
      for (int ni = 0; ni < 2; ++ni) {
        const f32x16 a = av[mi * 2 + ni];
        const int p = (wm * 2 + mi) * 4 + (wn * 2 + ni);
#pragma unroll
        for (int c4 = 0; c4 < 2; ++c4) {
          const int sl = l31 + 32 * h + 64 * c4;
          u32x4 v;
          v[0] = cvtpk(a[8 * c4 + 0], a[8 * c4 + 1]);
          v[1] = cvtpk(a[8 * c4 + 2], a[8 * c4 + 3]);
          v[2] = cvtpk(a[8 * c4 + 4], a[8 * c4 + 5]);
          v[3] = cvtpk(a[8 * c4 + 6], a[8 * c4 + 7]);
          *(u32x4*)(o_sh + p * 2048 + ((sl ^ (p & 7)) << 4)) = v;
        }
      }
    }
  }
  __syncthreads();

  // ---- phase B: wave (ztp = z-half of 64, kh = k-half of 512), 16x16x32 MFMA
  {
    const int ztp = wid & 1;
    const int kh = wid >> 1;
    const int zb = ztp * 4;                    // zt base (zt = 16 z's)
    const unsigned short* wq = w2T + lane * 8;
    const int p = lane & 15;
    const int g = lane >> 4;
    const int obase = p * 2048;
    const int oxor = p & 7;
    const int ks0 = kh * 16;

    bfx8 wA0 = *(const bfx8*)(wq + ((zb + 0) * 32 + ks0) * 512);
    bfx8 wA1 = *(const bfx8*)(wq + ((zb + 1) * 32 + ks0) * 512);
    bfx8 wA2 = *(const bfx8*)(wq + ((zb + 2) * 32 + ks0) * 512);
    bfx8 wA3 = *(const bfx8*)(wq + ((zb + 3) * 32 + ks0) * 512);
    bfx8 oA = *(const bfx8*)(o_sh + obase + ((((ks0 * 4 + g)) ^ oxor) << 4));

    fx4 az0 = {0.f,0.f,0.f,0.f}, az1 = {0.f,0.f,0.f,0.f};
    fx4 az2 = {0.f,0.f,0.f,0.f}, az3 = {0.f,0.f,0.f,0.f};
#pragma unroll
    for (int st = 0; st < 16; ++st) {
      bfx8 wB0, wB1, wB2, wB3, oB;
      if (st < 15) {
        const int nk = ks0 + st + 1;
        wB0 = *(const bfx8*)(wq + ((zb + 0) * 32 + nk) * 512);
        wB1 = *(const bfx8*)(wq + ((zb + 1) * 32 + nk) * 512);
        wB2 = *(const bfx8*)(wq + ((zb + 2) * 32 + nk) * 512);
        wB3 = *(const bfx8*)(wq + ((zb + 3) * 32 + nk) * 512);
        oB = *(const bfx8*)(o_sh + obase + (((nk * 4 + g) ^ oxor) << 4));
      }
      __builtin_amdgcn_s_setprio(1);
      az0 = __builtin_amdgcn_mfma_f32_16x16x32_bf16(wA0, oA, az0, 0, 0, 0);
      az1 = __builtin_amdgcn_mfma_f32_16x16x32_bf16(wA1, oA, az1, 0, 0, 0);
      az2 = __builtin_amdgcn_mfma_f32_16x16x32_bf16(wA2, oA, az2, 0, 0, 0);
      az3 = __builtin_amdgcn_mfma_f32_16x16x32_bf16(wA3, oA, az3, 0, 0, 0);
      __builtin_amdgcn_s_setprio(0);
      if (st < 15) { wA0 = wB0; wA1 = wB1; wA2 = wB2; wA3 = wB3; oA = oB; }
    }
    __syncthreads();   // all O reads done; [0,8K) reusable for partials

    // kh=1 waves publish partials (8 KB), kh=0 waves reduce + bias + store
    char* pb = smem + ztp * 4096;
    if (kh == 1) {
      *(fx4*)(pb + 0 * 1024 + lane * 16) = az0;
      *(fx4*)(pb + 1 * 1024 + lane * 16) = az1;
      *(fx4*)(pb + 2 * 1024 + lane * 16) = az2;
      *(fx4*)(pb + 3 * 1024 + lane * 16) = az3;
    }
    __syncthreads();
    if (kh == 0) {
      az0 += *(const fx4*)(pb + 0 * 1024 + lane * 16);
      az1 += *(const fx4*)(pb + 1 * 1024 + lane * 16);
      az2 += *(const fx4*)(pb + 2 * 1024 + lane * 16);
      az3 += *(const fx4*)(pb + 3 * 1024 + lane * 16);
      const int i = i0 + (p >> 2), j = j0 + (p & 3);
      float* op = out + (i * SDIM + j) * CZ;
      const int zq = g * 4;
      fx4 v;
      v = az0 + *(const fx4*)(bout + (zb + 0) * 16 + zq); *(fx4*)(op + (zb + 0) * 16 + zq) = v;
      v = az1 + *(const fx4*)(bout + (zb + 1) * 16 + zq); *(fx4*)(op + (zb + 1) * 16 + zq) = v;
      v = az2 + *(const fx4*)(bout + (zb + 2) * 16 + zq); *(fx4*)(op + (zb + 2) * 16 + zq) = v;
      v = az3 + *(const fx4*)(bout + (zb + 3) * 16 + zq); *(fx4*)(op + (zb + 3) * 16 + zq) = v;
    }
  }
}

extern "C" void kernel_launch(void* const* d_in, const int* in_sizes, int n_in,
                              void* d_out, int out_size, void* d_ws, size_t ws_size,
                              hipStream_t stream) {
  const float* m_si  = (const float*)d_in[0];
  const float* gamma = (const float*)d_in[1];
  const float* beta  = (const float*)d_in[2];
  const float* Wab   = (const float*)d_in[3];
  const float* Wout  = (const float*)d_in[4];
  const float* bout  = (const float*)d_in[5];
  float* out = (float*)d_out;

  char* ws = (char*)d_ws;
  unsigned short* a_t = (unsigned short*)ws;                    // 4 MB
  unsigned short* b_t = (unsigned short*)(ws + (4u << 20));     // 4 MB
  unsigned short* w2T = (unsigned short*)(ws + (8u << 20));     // 256 KB

  opm_prep<<<dim3(2 * SDIM + 32), dim3(256), 0, stream>>>(m_si, gamma, beta, Wab, Wout, a_t, b_t, w2T);
  opm_main<<<dim3(4096), dim3(256), 0, stream>>>(a_t, b_t, w2T, bout, out);
}

// Round 12
// 77.934 us; speedup vs baseline: 1.1961x; 1.1961x over previous
//
#include <hip/hip_runtime.h>

#define SDIM 256
#define NSEQ 256
#define CDIM 32
#define CZ 128
#define IB 8
#define JB 4

typedef __bf16 bfx8 __attribute__((ext_vector_type(8)));
typedef float fx4 __attribute__((ext_vector_type(4)));
typedef float f32x16 __attribute__((ext_vector_type(16)));
typedef unsigned int u32x4 __attribute__((ext_vector_type(4)));

__device__ __forceinline__ unsigned short f2bf(float f) {
  unsigned int u = __float_as_uint(f);
  u += 0x7fffu + ((u >> 16) & 1u);
  return (unsigned short)(u >> 16);
}

__device__ __forceinline__ unsigned int cvtpk(float lo, float hi) {
  unsigned int r;
  asm("v_cvt_pk_bf16_f32 %0, %1, %2" : "=v"(r) : "v"(lo), "v"(hi));
  return r;
}

// native-cast bf16 pack (NO inline asm — compiler emits the cvts; m240)
__device__ __forceinline__ bfx8 pack8(const fx4 lo, const fx4 hi) {
  bfx8 r;
  r[0] = (__bf16)lo[0]; r[1] = (__bf16)lo[1]; r[2] = (__bf16)lo[2]; r[3] = (__bf16)lo[3];
  r[4] = (__bf16)hi[0]; r[5] = (__bf16)hi[1]; r[6] = (__bf16)hi[2]; r[7] = (__bf16)hi[3];
  return r;
}

__device__ __forceinline__ void gload16(const void* g, void* l) {
  __builtin_amdgcn_global_load_lds((const __attribute__((address_space(1))) unsigned int*)g,
                                   (__attribute__((address_space(3))) unsigned int*)l,
                                   16, 0, 0);
}

// sigma(d,c): k' = e(c0,c1,c3) + 8*sl, sl = d + 32*c2 + 64*c4  (c2 = MFMA h-bit)

// ---------------- prep ----------------
// blocks [0,256): LN + ab projection via MFMA (one s per block)
// blocks [256,288): W_out -> w2T repack (4 z-rows each)
__global__ __launch_bounds__(256) void opm_prep(
    const float* __restrict__ m_si, const float* __restrict__ gamma, const float* __restrict__ beta,
    const float* __restrict__ Wab, const float* __restrict__ Wout,
    unsigned short* __restrict__ a_t, unsigned short* __restrict__ b_t,
    unsigned short* __restrict__ w2T)
{
  __shared__ __align__(16) char shbuf[8192];
  const int b = blockIdx.x;
  const int t = threadIdx.x;
  if (b < SDIM) {
    const int s = b;
    const int l = t & 63;
    const int w = t >> 6;          // 0..3
    const int nl = l & 15;         // row/col-in-tile
    const int cg = l >> 4;         // 0..3 c-octet

    // A-fragments: Wab[d][c], lane: row d = dt*16+nl, k = cg*8+e
    bfx8 afr[4];
#pragma unroll
    for (int dt = 0; dt < 4; ++dt) {
      const float* wr = Wab + (dt * 16 + nl) * 32 + cg * 8;
      afr[dt] = pack8(*(const fx4*)wr, *(const fx4*)(wr + 4));
    }
    const fx4 g0 = *(const fx4*)(gamma + cg * 8);
    const fx4 g1 = *(const fx4*)(gamma + cg * 8 + 4);
    const fx4 bt0 = *(const fx4*)(beta + cg * 8);
    const fx4 bt1 = *(const fx4*)(beta + cg * 8 + 4);

#pragma unroll
    for (int p = 0; p < 4; ++p) {
      const int n = p * 64 + w * 16 + nl;
      const float* xr = m_si + (s * 256 + n) * 32 + cg * 8;
      const fx4 v0 = *(const fx4*)xr;
      const fx4 v1 = *(const fx4*)(xr + 4);
      float ps  = v0[0] + v0[1] + v0[2] + v0[3] + v1[0] + v1[1] + v1[2] + v1[3];
      float ps2 = v0[0]*v0[0] + v0[1]*v0[1] + v0[2]*v0[2] + v0[3]*v0[3]
                + v1[0]*v1[0] + v1[1]*v1[1] + v1[2]*v1[2] + v1[3]*v1[3];
      ps  += __shfl_xor(ps, 16);  ps  += __shfl_xor(ps, 32);
      ps2 += __shfl_xor(ps2, 16); ps2 += __shfl_xor(ps2, 32);
      const float mu = ps * 0.03125f;
      const float var = ps2 * 0.03125f - mu * mu;
      const float inv = rsqrtf(var + 1e-5f);
      const fx4 e0 = (v0 - mu) * inv * g0 + bt0;
      const fx4 e1 = (v1 - mu) * inv * g1 + bt1;
      const bfx8 bfr = pack8(e0, e1);    // B-frag: col n, k = cg*8+e

      fx4 dz[4];
#pragma unroll
      for (int dt = 0; dt < 4; ++dt)
        dz[dt] = __builtin_amdgcn_mfma_f32_16x16x32_bf16(afr[dt], bfr, (fx4){0.f,0.f,0.f,0.f}, 0, 0, 0);

#pragma unroll
      for (int dt = 0; dt < 4; ++dt) {
#pragma unroll
        for (int r = 0; r < 4; ++r) {
          const int d = dt * 16 + cg * 4 + r;
          const unsigned short hv = f2bf(dz[dt][r]);
          if (d < 32) a_t[(s * 32 + d) * 256 + n] = hv;
          else        b_t[(s * 32 + (d - 32)) * 256 + n] = hv;
        }
      }
    }
  } else {
    // repack to w2T: elem (z, k') dest bits: e[0:2], zl[3:7], h[8], ks[9:14], zt[15:16]
    unsigned short* lin = (unsigned short*)shbuf;    // 8 KB
    const int blk = b - SDIM;                        // 0..31
    const float* wsrc = Wout + blk * 4096;
#pragma unroll
    for (int jj = 0; jj < 4; ++jj) {
      const int q = t + jj * 256;                    // fx4 id
      const fx4 v = ((const fx4*)wsrc)[q];
      unsigned short* dst = lin + q * 4;
      dst[0] = f2bf(v[0]); dst[1] = f2bf(v[1]); dst[2] = f2bf(v[2]); dst[3] = f2bf(v[3]);
    }
    __syncthreads();
    const int z0 = blk * 4;
#pragma unroll
    for (int w = 0; w < 2; ++w) {
      const int id = t + w * 256;        // 0..511
      const int lz = id & 3;
      const int hh = (id >> 2) & 1;
      const int ks = id >> 3;            // 0..63
      const int z = z0 + lz;
      unsigned short vals[8];
#pragma unroll
      for (int e = 0; e < 8; ++e) {
        const int kp = ks * 16 + hh * 8 + e;
        const int c = (kp & 3) | (((kp >> 8) & 1) << 2) | (((kp >> 2) & 1) << 3) | (((kp >> 9) & 1) << 4);
        const int d = (kp >> 3) & 31;
        vals[e] = lin[lz * 1024 + c * CDIM + d];
      }
      const int dest = ((z >> 5) << 15) + (ks << 9) + (hh << 8) + ((z & 31) << 3);
      *(u32x4*)(w2T + dest) = *(const u32x4*)vals;
    }
  }
}

// ---------------- main: 8x4 (i,j) tiles = 32 pairs/block, 32x32x16 MFMA ----------------
// (round-7 kernel verbatim — known good at 72.5 us)
__global__ __launch_bounds__(512, 4) void opm_main(
    const unsigned short* __restrict__ a_t, const unsigned short* __restrict__ b_t,
    const unsigned short* __restrict__ w2T, const float* __restrict__ bout,
    float* __restrict__ out)
{
  // O [0,64K) overlays staging: A0 [16K,32K) A1 [32K,48K) B0 [48K,56K) B1 [56K,64K)
  __shared__ __align__(16) char smem[65536];
  char* o_sh = smem;

  const int tid = threadIdx.x;
  const int lane = tid & 63;
  const int wid = tid >> 6;           // 0..7
  const int l31 = lane & 31;
  const int h = lane >> 5;

  // 2-D XCD blocking: each XCD owns 16i x 16j chunk (3.25 MB working set < 4 MB L2)
  const int bxr = blockIdx.x;
  const int xc = bxr & 7;
  const int q8 = bxr >> 3;            // 0..255
  const int it = q8 >> 4;             // 0..15
  const int jt = q8 & 15;             // 0..15
  const int i0 = ((xc & 1) * 16 + it) * IB;
  const int j0 = ((xc >> 1) * 16 + jt) * JB;

  const int wm = wid >> 1;            // 0..3: M 64-row group
  const int wn = wid & 1;             // 0..1: N 64-row group
  const int wbase = wid * 1024;       // wave-uniform LDS staging offset

  f32x16 acc00 = {}, acc01 = {}, acc10 = {}, acc11 = {};

  // chunk q (16B) at LDS offset q*16 holds global n-group gs = (q&3) ^ ((q>>3)&3)
  auto STAGE = [&](int buf, int nc) {
    const int nbase = nc * 32;
    char* A = smem + 16384 + buf * 16384;
    char* B = smem + 49152 + buf * 8192;
#pragma unroll
    for (int pass = 0; pass < 2; ++pass) {
      const int q = pass * 512 + tid;
      const int row = q >> 2;
      const int gs = (q & 3) ^ ((q >> 3) & 3);
      const unsigned short* src = a_t + ((i0 + (row >> 5)) * 32 + (row & 31)) * 256 + nbase + gs * 8;
      gload16(src, A + pass * 8192 + wbase);
    }
    {
      const int q = tid;
      const int row = q >> 2;
      const int gs = (q & 3) ^ ((q >> 3) & 3);
      const unsigned short* src = b_t + ((j0 + (row >> 5)) * 32 + (row & 31)) * 256 + nbase + gs * 8;
      gload16(src, B + wbase);
    }
  };

  auto COMPUTE = [&](int buf) {
    char* A = smem + 16384 + buf * 16384;
    char* B = smem + 49152 + buf * 8192;
#pragma unroll
    for (int ks = 0; ks < 2; ++ks) {
      const int s = ks * 2 + h;
      bfx8 af0, af1, bf0, bf1;
      { const int r = wm * 64 + l31;      af0 = *(const bfx8*)(A + r * 64 + (((s ^ (r >> 1)) & 3) << 4)); }
      { const int r = wm * 64 + 32 + l31; af1 = *(const bfx8*)(A + r * 64 + (((s ^ (r >> 1)) & 3) << 4)); }
      { const int r = wn * 64 + l31;      bf0 = *(const bfx8*)(B + r * 64 + (((s ^ (r >> 1)) & 3) << 4)); }
      { const int r = wn * 64 + 32 + l31; bf1 = *(const bfx8*)(B + r * 64 + (((s ^ (r >> 1)) & 3) << 4)); }
      __builtin_amdgcn_s_setprio(1);
      acc00 = __builtin_amdgcn_mfma_f32_32x32x16_bf16(af0, bf0, acc00, 0, 0, 0);
      acc01 = __builtin_amdgcn_mfma_f32_32x32x16_bf16(af0, bf1, acc01, 0, 0, 0);
      acc10 = __builtin_amdgcn_mfma_f32_32x32x16_bf16(af1, bf0, acc10, 0, 0, 0);
      acc11 = __builtin_amdgcn_mfma_f32_32x32x16_bf16(af1, bf1, acc11, 0, 0, 0);
      __builtin_amdgcn_s_setprio(0);
    }
  };

  STAGE(0, 0);
#pragma unroll 2
  for (int t = 0; t < 8; ++t) {
    if (t < 7) {
      STAGE((t + 1) & 1, t + 1);
      asm volatile("s_waitcnt vmcnt(3)" ::: "memory");
    } else {
      asm volatile("s_waitcnt vmcnt(0)" ::: "memory");
    }
    __builtin_amdgcn_s_barrier();
    asm volatile("" ::: "memory");
    COMPUTE(t & 1);
    asm volatile("s_waitcnt lgkmcnt(0)" ::: "memory");
    __builtin_amdgcn_s_barrier();
  }

  // ---- O -> LDS: pair p at [p*2048 + ((d + 32*c2 + 64*c4) ^ (p&7))*16]
  {
    const f32x16 av[4] = { acc00 * 0.00390625f, acc01 * 0.00390625f,
                           acc10 * 0.00390625f, acc11 * 0.00390625f };
#pragma unroll
    for (int mi = 0; mi < 2; ++mi) {
#pragma unroll
      for (int ni = 0; ni < 2; ++ni) {
        const f32x16 a = av[mi * 2 + ni];
        const int p = (wm * 2 + mi) * 4 + (wn * 2 + ni);
#pragma unroll
        for (int c4 = 0; c4 < 2; ++c4) {
          const int sl = l31 + 32 * h + 64 * c4;
          u32x4 v;
          v[0] = cvtpk(a[8 * c4 + 0], a[8 * c4 + 1]);
          v[1] = cvtpk(a[8 * c4 + 2], a[8 * c4 + 3]);
          v[2] = cvtpk(a[8 * c4 + 4], a[8 * c4 + 5]);
          v[3] = cvtpk(a[8 * c4 + 6], a[8 * c4 + 7]);
          *(u32x4*)(o_sh + p * 2048 + ((sl ^ (p & 7)) << 4)) = v;
        }
      }
    }
  }
  __syncthreads();

  // ---- phase B: waves (ztp 0-1 = z'-tile pair, kh 0-3 = K-quarter); of shared by 2 MFMAs
  {
    const int ztp = wid & 1;
    const int kh = wid >> 1;
    const unsigned short* wpa = w2T + ((ztp * 2 + 0) << 15) + (h << 8) + (l31 << 3);
    const unsigned short* wpb = w2T + ((ztp * 2 + 1) << 15) + (h << 8) + (l31 << 3);
    const int obase = l31 * 2048;
    const int oxor = l31 & 7;
    const int ks0 = kh * 16;

    bfx8 wa[4], wb[4];
#pragma unroll
    for (int q = 0; q < 4; ++q) {
      wa[q] = *(const bfx8*)(wpa + ((ks0 + q) << 9));
      wb[q] = *(const bfx8*)(wpb + ((ks0 + q) << 9));
    }
    bfx8 oc = *(const bfx8*)(o_sh + obase + ((((ks0 << 1) + h) ^ oxor) << 4));
    bfx8 on = *(const bfx8*)(o_sh + obase + (((((ks0 + 1) << 1) + h) ^ oxor) << 4));

    f32x16 za = {}, zb = {};
#pragma unroll
    for (int st = 0; st < 16; ++st) {
      const int q = st & 3;
      __builtin_amdgcn_s_setprio(1);
      za = __builtin_amdgcn_mfma_f32_32x32x16_bf16(wa[q], oc, za, 0, 0, 0);
      zb = __builtin_amdgcn_mfma_f32_32x32x16_bf16(wb[q], oc, zb, 0, 0, 0);
      __builtin_amdgcn_s_setprio(0);
      oc = on;
      if (st < 14) on = *(const bfx8*)(o_sh + obase + (((((ks0 + st + 2) << 1) + h) ^ oxor) << 4));
      if (st < 12) {
        wa[q] = *(const bfx8*)(wpa + ((ks0 + st + 4) << 9));
        wb[q] = *(const bfx8*)(wpb + ((ks0 + st + 4) << 9));
      }
    }
    __syncthreads();   // all O reads done; o_sh reusable for partials

    // pairwise kh reduction: (0<-1), (2<-3), then (0<-2); partials fx4 [slot][zs][g2*2+h][p]
    const int slot = (kh >> 1) * 2 + ztp;
    auto PWRITE = [&](char* base) {
#pragma unroll
      for (int zs = 0; zs < 2; ++zs) {
        const f32x16& A = zs ? zb : za;
#pragma unroll
        for (int g2 = 0; g2 < 4; ++g2) {
          fx4 v = { A[4 * g2], A[4 * g2 + 1], A[4 * g2 + 2], A[4 * g2 + 3] };
          *(fx4*)(base + zs * 4096 + (((g2 * 2 + h) * 32 + l31) << 4)) = v;
        }
      }
    };
    auto PADD = [&](const char* base) {
#pragma unroll
      for (int zs = 0; zs < 2; ++zs) {
        f32x16& A = zs ? zb : za;
#pragma unroll
        for (int g2 = 0; g2 < 4; ++g2) {
          const fx4 v = *(const fx4*)(base + zs * 4096 + (((g2 * 2 + h) * 32 + l31) << 4));
          A[4 * g2 + 0] += v[0]; A[4 * g2 + 1] += v[1];
          A[4 * g2 + 2] += v[2]; A[4 * g2 + 3] += v[3];
        }
      }
    };
    if (kh & 1) PWRITE(o_sh + slot * 8192);
    __syncthreads();
    if (!(kh & 1)) {
      PADD(o_sh + slot * 8192);
      if (kh == 2) PWRITE(o_sh + 32768 + ztp * 8192);
    }
    __syncthreads();
    if (kh == 0) {
      PADD(o_sh + 32768 + ztp * 8192);
      const int i = i0 + (l31 >> 2), j = j0 + (l31 & 3);
      float* op = out + (i * SDIM + j) * CZ + ztp * 64;
      const float* bp = bout + ztp * 64;
#pragma unroll
      for (int zs = 0; zs < 2; ++zs) {
        const f32x16& A = zs ? zb : za;
#pragma unroll
        for (int g2 = 0; g2 < 4; ++g2) {
          const int zl = zs * 32 + g2 * 8 + h * 4;
          fx4 v = { A[4 * g2], A[4 * g2 + 1], A[4 * g2 + 2], A[4 * g2 + 3] };
          v += *(const fx4*)(bp + zl);
          *(fx4*)(op + zl) = v;
        }
      }
    }
  }
}

extern "C" void kernel_launch(void* const* d_in, const int* in_sizes, int n_in,
                              void* d_out, int out_size, void* d_ws, size_t ws_size,
                              hipStream_t stream) {
  const float* m_si  = (const float*)d_in[0];
  const float* gamma = (const float*)d_in[1];
  const float* beta  = (const float*)d_in[2];
  const float* Wab   = (const float*)d_in[3];
  const float* Wout  = (const float*)d_in[4];
  const float* bout  = (const float*)d_in[5];
  float* out = (float*)d_out;

  char* ws = (char*)d_ws;
  unsigned short* a_t = (unsigned short*)ws;                    // 4 MB
  unsigned short* b_t = (unsigned short*)(ws + (4u << 20));     // 4 MB
  unsigned short* w2T = (unsigned short*)(ws + (8u << 20));     // 256 KB

  opm_prep<<<dim3(SDIM + 32), dim3(256), 0, stream>>>(m_si, gamma, beta, Wab, Wout, a_t, b_t, w2T);
  opm_main<<<dim3(2048), dim3(512), 0, stream>>>(a_t, b_t, w2T, bout, out);
}

// Round 13
// 74.985 us; speedup vs baseline: 1.2432x; 1.0393x over previous
//
#include <hip/hip_runtime.h>

#define SDIM 256
#define NSEQ 256
#define CDIM 32
#define CZ 128
#define IB 8
#define JB 4

typedef __bf16 bfx8 __attribute__((ext_vector_type(8)));
typedef float fx4 __attribute__((ext_vector_type(4)));
typedef float f32x16 __attribute__((ext_vector_type(16)));
typedef unsigned int u32x4 __attribute__((ext_vector_type(4)));

__device__ __forceinline__ unsigned short f2bf(float f) {
  unsigned int u = __float_as_uint(f);
  u += 0x7fffu + ((u >> 16) & 1u);
  return (unsigned short)(u >> 16);
}

__device__ __forceinline__ unsigned int cvtpk(float lo, float hi) {
  unsigned int r;
  asm("v_cvt_pk_bf16_f32 %0, %1, %2" : "=v"(r) : "v"(lo), "v"(hi));
  return r;
}

// native-cast bf16 pack (NO inline asm — compiler emits the cvts; m240)
__device__ __forceinline__ bfx8 pack8(const fx4 lo, const fx4 hi) {
  bfx8 r;
  r[0] = (__bf16)lo[0]; r[1] = (__bf16)lo[1]; r[2] = (__bf16)lo[2]; r[3] = (__bf16)lo[3];
  r[4] = (__bf16)hi[0]; r[5] = (__bf16)hi[1]; r[6] = (__bf16)hi[2]; r[7] = (__bf16)hi[3];
  return r;
}

__device__ __forceinline__ void gload16(const void* g, void* l) {
  __builtin_amdgcn_global_load_lds((const __attribute__((address_space(1))) unsigned int*)g,
                                   (__attribute__((address_space(3))) unsigned int*)l,
                                   16, 0, 0);
}

// sigma(d,c): k' = e(c0,c1,c3) + 8*sl, sl = d + 32*c2 + 64*c4  (c2 = MFMA h-bit)

// ---------------- prep (round-12, verified) ----------------
__global__ __launch_bounds__(256) void opm_prep(
    const float* __restrict__ m_si, const float* __restrict__ gamma, const float* __restrict__ beta,
    const float* __restrict__ Wab, const float* __restrict__ Wout,
    unsigned short* __restrict__ a_t, unsigned short* __restrict__ b_t,
    unsigned short* __restrict__ w2T)
{
  __shared__ __align__(16) char shbuf[8192];
  const int b = blockIdx.x;
  const int t = threadIdx.x;
  if (b < SDIM) {
    const int s = b;
    const int l = t & 63;
    const int w = t >> 6;          // 0..3
    const int nl = l & 15;         // row/col-in-tile
    const int cg = l >> 4;         // 0..3 c-octet

    bfx8 afr[4];
#pragma unroll
    for (int dt = 0; dt < 4; ++dt) {
      const float* wr = Wab + (dt * 16 + nl) * 32 + cg * 8;
      afr[dt] = pack8(*(const fx4*)wr, *(const fx4*)(wr + 4));
    }
    const fx4 g0 = *(const fx4*)(gamma + cg * 8);
    const fx4 g1 = *(const fx4*)(gamma + cg * 8 + 4);
    const fx4 bt0 = *(const fx4*)(beta + cg * 8);
    const fx4 bt1 = *(const fx4*)(beta + cg * 8 + 4);

#pragma unroll
    for (int p = 0; p < 4; ++p) {
      const int n = p * 64 + w * 16 + nl;
      const float* xr = m_si + (s * 256 + n) * 32 + cg * 8;
      const fx4 v0 = *(const fx4*)xr;
      const fx4 v1 = *(const fx4*)(xr + 4);
      float ps  = v0[0] + v0[1] + v0[2] + v0[3] + v1[0] + v1[1] + v1[2] + v1[3];
      float ps2 = v0[0]*v0[0] + v0[1]*v0[1] + v0[2]*v0[2] + v0[3]*v0[3]
                + v1[0]*v1[0] + v1[1]*v1[1] + v1[2]*v1[2] + v1[3]*v1[3];
      ps  += __shfl_xor(ps, 16);  ps  += __shfl_xor(ps, 32);
      ps2 += __shfl_xor(ps2, 16); ps2 += __shfl_xor(ps2, 32);
      const float mu = ps * 0.03125f;
      const float var = ps2 * 0.03125f - mu * mu;
      const float inv = rsqrtf(var + 1e-5f);
      const fx4 e0 = (v0 - mu) * inv * g0 + bt0;
      const fx4 e1 = (v1 - mu) * inv * g1 + bt1;
      const bfx8 bfr = pack8(e0, e1);

      fx4 dz[4];
#pragma unroll
      for (int dt = 0; dt < 4; ++dt)
        dz[dt] = __builtin_amdgcn_mfma_f32_16x16x32_bf16(afr[dt], bfr, (fx4){0.f,0.f,0.f,0.f}, 0, 0, 0);

#pragma unroll
      for (int dt = 0; dt < 4; ++dt) {
#pragma unroll
        for (int r = 0; r < 4; ++r) {
          const int d = dt * 16 + cg * 4 + r;
          const unsigned short hv = f2bf(dz[dt][r]);
          if (d < 32) a_t[(s * 32 + d) * 256 + n] = hv;
          else        b_t[(s * 32 + (d - 32)) * 256 + n] = hv;
        }
      }
    }
  } else {
    unsigned short* lin = (unsigned short*)shbuf;    // 8 KB
    const int blk = b - SDIM;                        // 0..31
    const float* wsrc = Wout + blk * 4096;
#pragma unroll
    for (int jj = 0; jj < 4; ++jj) {
      const int q = t + jj * 256;
      const fx4 v = ((const fx4*)wsrc)[q];
      unsigned short* dst = lin + q * 4;
      dst[0] = f2bf(v[0]); dst[1] = f2bf(v[1]); dst[2] = f2bf(v[2]); dst[3] = f2bf(v[3]);
    }
    __syncthreads();
    const int z0 = blk * 4;
#pragma unroll
    for (int w = 0; w < 2; ++w) {
      const int id = t + w * 256;
      const int lz = id & 3;
      const int hh = (id >> 2) & 1;
      const int ks = id >> 3;
      const int z = z0 + lz;
      unsigned short vals[8];
#pragma unroll
      for (int e = 0; e < 8; ++e) {
        const int kp = ks * 16 + hh * 8 + e;
        const int c = (kp & 3) | (((kp >> 8) & 1) << 2) | (((kp >> 2) & 1) << 3) | (((kp >> 9) & 1) << 4);
        const int d = (kp >> 3) & 31;
        vals[e] = lin[lz * 1024 + c * CDIM + d];
      }
      const int dest = ((z >> 5) << 15) + (ks << 9) + (hh << 8) + ((z & 31) << 3);
      *(u32x4*)(w2T + dest) = *(const u32x4*)vals;
    }
  }
}

// ---------------- main: 8x4 (i,j) tiles; T3/T4 phase-A: triple-buffer, counted vmcnt, split phases ----------------
__global__ __launch_bounds__(512, 4) void opm_main(
    const unsigned short* __restrict__ a_t, const unsigned short* __restrict__ b_t,
    const unsigned short* __restrict__ w2T, const float* __restrict__ bout,
    float* __restrict__ out)
{
  // staging: A0/A1/A2 at [0,48K), B0/B1/B2 at [48K,72K); O overlays [0,64K) after phase A
  __shared__ __align__(16) char smem[73728];
  char* o_sh = smem;

  const int tid = threadIdx.x;
  const int lane = tid & 63;
  const int wid = tid >> 6;           // 0..7
  const int l31 = lane & 31;
  const int h = lane >> 5;

  // 2-D XCD blocking: each XCD owns 16i x 16j chunk (3.25 MB working set < 4 MB L2)
  const int bxr = blockIdx.x;
  const int xc = bxr & 7;
  const int q8 = bxr >> 3;
  const int it = q8 >> 4;
  const int jt = q8 & 15;
  const int i0 = ((xc & 1) * 16 + it) * IB;
  const int j0 = ((xc >> 1) * 16 + jt) * JB;

  const int wm = wid >> 1;            // 0..3: M 64-row group
  const int wn = wid & 1;             // 0..1: N 64-row group
  const int wbase = wid * 1024;

  f32x16 acc00 = {}, acc01 = {}, acc10 = {}, acc11 = {};

  // chunk q (16B) at LDS offset q*16 holds global n-group gs = (q&3) ^ ((q>>3)&3)
  auto STAGE_A = [&](int buf, int nc) {
    const int nbase = nc * 32;
    char* A = smem + buf * 16384;
#pragma unroll
    for (int pass = 0; pass < 2; ++pass) {
      const int q = pass * 512 + tid;
      const int row = q >> 2;
      const int gs = (q & 3) ^ ((q >> 3) & 3);
      const unsigned short* src = a_t + ((i0 + (row >> 5)) * 32 + (row & 31)) * 256 + nbase + gs * 8;
      gload16(src, A + pass * 8192 + wbase);
    }
  };
  auto STAGE_B = [&](int buf, int nc) {
    const int nbase = nc * 32;
    char* B = smem + 49152 + buf * 8192;
    const int q = tid;
    const int row = q >> 2;
    const int gs = (q & 3) ^ ((q >> 3) & 3);
    const unsigned short* src = b_t + ((j0 + (row >> 5)) * 32 + (row & 31)) * 256 + nbase + gs * 8;
    gload16(src, B + wbase);
  };

  // one K-half (4 ds_read_b128 + 4 MFMA)
  auto HALF = [&](int buf, int ks) {
    char* A = smem + buf * 16384;
    char* B = smem + 49152 + buf * 8192;
    const int s = ks * 2 + h;
    bfx8 af0, af1, bf0, bf1;
    { const int r = wm * 64 + l31;      af0 = *(const bfx8*)(A + r * 64 + (((s ^ (r >> 1)) & 3) << 4)); }
    { const int r = wm * 64 + 32 + l31; af1 = *(const bfx8*)(A + r * 64 + (((s ^ (r >> 1)) & 3) << 4)); }
    { const int r = wn * 64 + l31;      bf0 = *(const bfx8*)(B + r * 64 + (((s ^ (r >> 1)) & 3) << 4)); }
    { const int r = wn * 64 + 32 + l31; bf1 = *(const bfx8*)(B + r * 64 + (((s ^ (r >> 1)) & 3) << 4)); }
    __builtin_amdgcn_s_setprio(1);
    acc00 = __builtin_amdgcn_mfma_f32_32x32x16_bf16(af0, bf0, acc00, 0, 0, 0);
    acc01 = __builtin_amdgcn_mfma_f32_32x32x16_bf16(af0, bf1, acc01, 0, 0, 0);
    acc10 = __builtin_amdgcn_mfma_f32_32x32x16_bf16(af1, bf0, acc10, 0, 0, 0);
    acc11 = __builtin_amdgcn_mfma_f32_32x32x16_bf16(af1, bf1, acc11, 0, 0, 0);
    __builtin_amdgcn_s_setprio(0);
  };

  // prologue: chunks 0 and 1 in flight (6 loads/thread outstanding)
  STAGE_A(0, 0); STAGE_B(0, 0);
  STAGE_A(1, 1); STAGE_B(1, 1);

#pragma unroll
  for (int c = 0; c < 8; ++c) {
    const int buf = c % 3;
    // ---- P0: issue next A-stage, counted wait for chunk c, half 0
    if (c + 2 < 8) STAGE_A((c + 2) % 3, c + 2);
    if (c <= 5)      { asm volatile("s_waitcnt vmcnt(5)" ::: "memory"); }
    else if (c == 6) { asm volatile("s_waitcnt vmcnt(3)" ::: "memory"); }
    else             { asm volatile("s_waitcnt vmcnt(0)" ::: "memory"); }
    __builtin_amdgcn_s_barrier();
    asm volatile("" ::: "memory");
    HALF(buf, 0);
    asm volatile("s_waitcnt lgkmcnt(0)" ::: "memory");
    __builtin_amdgcn_s_barrier();
    // ---- P1: issue next B-stage, half 1
    if (c + 2 < 8) STAGE_B((c + 2) % 3, c + 2);
    asm volatile("" ::: "memory");
    HALF(buf, 1);
    asm volatile("s_waitcnt lgkmcnt(0)" ::: "memory");
    __builtin_amdgcn_s_barrier();
  }
  __syncthreads();   // drain before O overlays staging

  // ---- O -> LDS: pair p at [p*2048 + ((d + 32*c2 + 64*c4) ^ (p&7))*16]
  {
    const f32x16 av[4] = { acc00 * 0.00390625f, acc01 * 0.00390625f,
                           acc10 * 0.00390625f, acc11 * 0.00390625f };
#pragma unroll
    for (int mi = 0; mi < 2; ++mi) {
#pragma unroll
      for (int ni = 0; ni < 2; ++ni) {
        const f32x16 a = av[mi * 2 + ni];
        const int p = (wm * 2 + mi) * 4 + (wn * 2 + ni);
#pragma unroll
        for (int c4 = 0; c4 < 2; ++c4) {
          const int sl = l31 + 32 * h + 64 * c4;
          u32x4 v;
          v[0] = cvtpk(a[8 * c4 + 0], a[8 * c4 + 1]);
          v[1] = cvtpk(a[8 * c4 + 2], a[8 * c4 + 3]);
          v[2] = cvtpk(a[8 * c4 + 4], a[8 * c4 + 5]);
          v[3] = cvtpk(a[8 * c4 + 6], a[8 * c4 + 7]);
          *(u32x4*)(o_sh + p * 2048 + ((sl ^ (p & 7)) << 4)) = v;
        }
      }
    }
  }
  __syncthreads();

  // ---- phase B (round-7, verified): waves (ztp, kh); of shared by 2 MFMAs
  {
    const int ztp = wid & 1;
    const int kh = wid >> 1;
    const unsigned short* wpa = w2T + ((ztp * 2 + 0) << 15) + (h << 8) + (l31 << 3);
    const unsigned short* wpb = w2T + ((ztp * 2 + 1) << 15) + (h << 8) + (l31 << 3);
    const int obase = l31 * 2048;
    const int oxor = l31 & 7;
    const int ks0 = kh * 16;

    bfx8 wa[4], wb[4];
#pragma unroll
    for (int q = 0; q < 4; ++q) {
      wa[q] = *(const bfx8*)(wpa + ((ks0 + q) << 9));
      wb[q] = *(const bfx8*)(wpb + ((ks0 + q) << 9));
    }
    bfx8 oc = *(const bfx8*)(o_sh + obase + ((((ks0 << 1) + h) ^ oxor) << 4));
    bfx8 on = *(const bfx8*)(o_sh + obase + (((((ks0 + 1) << 1) + h) ^ oxor) << 4));

    f32x16 za = {}, zb = {};
#pragma unroll
    for (int st = 0; st < 16; ++st) {
      const int q = st & 3;
      __builtin_amdgcn_s_setprio(1);
      za = __builtin_amdgcn_mfma_f32_32x32x16_bf16(wa[q], oc, za, 0, 0, 0);
      zb = __builtin_amdgcn_mfma_f32_32x32x16_bf16(wb[q], oc, zb, 0, 0, 0);
      __builtin_amdgcn_s_setprio(0);
      oc = on;
      if (st < 14) on = *(const bfx8*)(o_sh + obase + (((((ks0 + st + 2) << 1) + h) ^ oxor) << 4));
      if (st < 12) {
        wa[q] = *(const bfx8*)(wpa + ((ks0 + st + 4) << 9));
        wb[q] = *(const bfx8*)(wpb + ((ks0 + st + 4) << 9));
      }
    }
    __syncthreads();   // all O reads done; o_sh reusable for partials

    const int slot = (kh >> 1) * 2 + ztp;
    auto PWRITE = [&](char* base) {
#pragma unroll
      for (int zs = 0; zs < 2; ++zs) {
        const f32x16& A = zs ? zb : za;
#pragma unroll
        for (int g2 = 0; g2 < 4; ++g2) {
          fx4 v = { A[4 * g2], A[4 * g2 + 1], A[4 * g2 + 2], A[4 * g2 + 3] };
          *(fx4*)(base + zs * 4096 + (((g2 * 2 + h) * 32 + l31) << 4)) = v;
        }
      }
    };
    auto PADD = [&](const char* base) {
#pragma unroll
      for (int zs = 0; zs < 2; ++zs) {
        f32x16& A = zs ? zb : za;
#pragma unroll
        for (int g2 = 0; g2 < 4; ++g2) {
          const fx4 v = *(const fx4*)(base + zs * 4096 + (((g2 * 2 + h) * 32 + l31) << 4));
          A[4 * g2 + 0] += v[0]; A[4 * g2 + 1] += v[1];
          A[4 * g2 + 2] += v[2]; A[4 * g2 + 3] += v[3];
        }
      }
    };
    if (kh & 1) PWRITE(o_sh + slot * 8192);
    __syncthreads();
    if (!(kh & 1)) {
      PADD(o_sh + slot * 8192);
      if (kh == 2) PWRITE(o_sh + 32768 + ztp * 8192);
    }
    __syncthreads();
    if (kh == 0) {
      PADD(o_sh + 32768 + ztp * 8192);
      const int i = i0 + (l31 >> 2), j = j0 + (l31 & 3);
      float* op = out + (i * SDIM + j) * CZ + ztp * 64;
      const float* bp = bout + ztp * 64;
#pragma unroll
      for (int zs = 0; zs < 2; ++zs) {
        const f32x16& A = zs ? zb : za;
#pragma unroll
        for (int g2 = 0; g2 < 4; ++g2) {
          const int zl = zs * 32 + g2 * 8 + h * 4;
          fx4 v = { A[4 * g2], A[4 * g2 + 1], A[4 * g2 + 2], A[4 * g2 + 3] };
          v += *(const fx4*)(bp + zl);
          *(fx4*)(op + zl) = v;
        }
      }
    }
  }
}

extern "C" void kernel_launch(void* const* d_in, const int* in_sizes, int n_in,
                              void* d_out, int out_size, void* d_ws, size_t ws_size,
                              hipStream_t stream) {
  const float* m_si  = (const float*)d_in[0];
  const float* gamma = (const float*)d_in[1];
  const float* beta  = (const float*)d_in[2];
  const float* Wab   = (const float*)d_in[3];
  const float* Wout  = (const float*)d_in[4];
  const float* bout  = (const float*)d_in[5];
  float* out = (float*)d_out;

  char* ws = (char*)d_ws;
  unsigned short* a_t = (unsigned short*)ws;                    // 4 MB
  unsigned short* b_t = (unsigned short*)(ws + (4u << 20));     // 4 MB
  unsigned short* w2T = (unsigned short*)(ws + (8u << 20));     // 256 KB

  opm_prep<<<dim3(SDIM + 32), dim3(256), 0, stream>>>(m_si, gamma, beta, Wab, Wout, a_t, b_t, w2T);
  opm_main<<<dim3(2048), dim3(512), 0, stream>>>(a_t, b_t, w2T, bout, out);
}

// Round 14
// 73.096 us; speedup vs baseline: 1.2753x; 1.0258x over previous
//
#include <hip/hip_runtime.h>

#define SDIM 256
#define NSEQ 256
#define CDIM 32
#define CZ 128
#define IB 8
#define JB 8

typedef __bf16 bfx8 __attribute__((ext_vector_type(8)));
typedef float fx4 __attribute__((ext_vector_type(4)));
typedef float f32x16 __attribute__((ext_vector_type(16)));
typedef unsigned int u32x4 __attribute__((ext_vector_type(4)));

__device__ __forceinline__ unsigned short f2bf(float f) {
  unsigned int u = __float_as_uint(f);
  u += 0x7fffu + ((u >> 16) & 1u);
  return (unsigned short)(u >> 16);
}

__device__ __forceinline__ unsigned int cvtpk(float lo, float hi) {
  unsigned int r;
  asm("v_cvt_pk_bf16_f32 %0, %1, %2" : "=v"(r) : "v"(lo), "v"(hi));
  return r;
}

// native-cast bf16 pack (NO inline asm — compiler emits the cvts; m240)
__device__ __forceinline__ bfx8 pack8(const fx4 lo, const fx4 hi) {
  bfx8 r;
  r[0] = (__bf16)lo[0]; r[1] = (__bf16)lo[1]; r[2] = (__bf16)lo[2]; r[3] = (__bf16)lo[3];
  r[4] = (__bf16)hi[0]; r[5] = (__bf16)hi[1]; r[6] = (__bf16)hi[2]; r[7] = (__bf16)hi[3];
  return r;
}

__device__ __forceinline__ void gload16(const void* g, void* l) {
  __builtin_amdgcn_global_load_lds((const __attribute__((address_space(1))) unsigned int*)g,
                                   (__attribute__((address_space(3))) unsigned int*)l,
                                   16, 0, 0);
}

// sigma(d,c): k' = e(c0,c1,c3) + 8*sl, sl = d + 32*c2 + 64*c4  (c2 = MFMA h-bit)

// ---------------- prep (round-12, verified) ----------------
__global__ __launch_bounds__(256) void opm_prep(
    const float* __restrict__ m_si, const float* __restrict__ gamma, const float* __restrict__ beta,
    const float* __restrict__ Wab, const float* __restrict__ Wout,
    unsigned short* __restrict__ a_t, unsigned short* __restrict__ b_t,
    unsigned short* __restrict__ w2T)
{
  __shared__ __align__(16) char shbuf[8192];
  const int b = blockIdx.x;
  const int t = threadIdx.x;
  if (b < SDIM) {
    const int s = b;
    const int l = t & 63;
    const int w = t >> 6;          // 0..3
    const int nl = l & 15;         // row/col-in-tile
    const int cg = l >> 4;         // 0..3 c-octet

    bfx8 afr[4];
#pragma unroll
    for (int dt = 0; dt < 4; ++dt) {
      const float* wr = Wab + (dt * 16 + nl) * 32 + cg * 8;
      afr[dt] = pack8(*(const fx4*)wr, *(const fx4*)(wr + 4));
    }
    const fx4 g0 = *(const fx4*)(gamma + cg * 8);
    const fx4 g1 = *(const fx4*)(gamma + cg * 8 + 4);
    const fx4 bt0 = *(const fx4*)(beta + cg * 8);
    const fx4 bt1 = *(const fx4*)(beta + cg * 8 + 4);

#pragma unroll
    for (int p = 0; p < 4; ++p) {
      const int n = p * 64 + w * 16 + nl;
      const float* xr = m_si + (s * 256 + n) * 32 + cg * 8;
      const fx4 v0 = *(const fx4*)xr;
      const fx4 v1 = *(const fx4*)(xr + 4);
      float ps  = v0[0] + v0[1] + v0[2] + v0[3] + v1[0] + v1[1] + v1[2] + v1[3];
      float ps2 = v0[0]*v0[0] + v0[1]*v0[1] + v0[2]*v0[2] + v0[3]*v0[3]
                + v1[0]*v1[0] + v1[1]*v1[1] + v1[2]*v1[2] + v1[3]*v1[3];
      ps  += __shfl_xor(ps, 16);  ps  += __shfl_xor(ps, 32);
      ps2 += __shfl_xor(ps2, 16); ps2 += __shfl_xor(ps2, 32);
      const float mu = ps * 0.03125f;
      const float var = ps2 * 0.03125f - mu * mu;
      const float inv = rsqrtf(var + 1e-5f);
      const fx4 e0 = (v0 - mu) * inv * g0 + bt0;
      const fx4 e1 = (v1 - mu) * inv * g1 + bt1;
      const bfx8 bfr = pack8(e0, e1);

      fx4 dz[4];
#pragma unroll
      for (int dt = 0; dt < 4; ++dt)
        dz[dt] = __builtin_amdgcn_mfma_f32_16x16x32_bf16(afr[dt], bfr, (fx4){0.f,0.f,0.f,0.f}, 0, 0, 0);

#pragma unroll
      for (int dt = 0; dt < 4; ++dt) {
#pragma unroll
        for (int r = 0; r < 4; ++r) {
          const int d = dt * 16 + cg * 4 + r;
          const unsigned short hv = f2bf(dz[dt][r]);
          if (d < 32) a_t[(s * 32 + d) * 256 + n] = hv;
          else        b_t[(s * 32 + (d - 32)) * 256 + n] = hv;
        }
      }
    }
  } else {
    unsigned short* lin = (unsigned short*)shbuf;    // 8 KB
    const int blk = b - SDIM;                        // 0..31
    const float* wsrc = Wout + blk * 4096;
#pragma unroll
    for (int jj = 0; jj < 4; ++jj) {
      const int q = t + jj * 256;
      const fx4 v = ((const fx4*)wsrc)[q];
      unsigned short* dst = lin + q * 4;
      dst[0] = f2bf(v[0]); dst[1] = f2bf(v[1]); dst[2] = f2bf(v[2]); dst[3] = f2bf(v[3]);
    }
    __syncthreads();
    const int z0 = blk * 4;
#pragma unroll
    for (int w = 0; w < 2; ++w) {
      const int id = t + w * 256;
      const int lz = id & 3;
      const int hh = (id >> 2) & 1;
      const int ks = id >> 3;
      const int z = z0 + lz;
      unsigned short vals[8];
#pragma unroll
      for (int e = 0; e < 8; ++e) {
        const int kp = ks * 16 + hh * 8 + e;
        const int c = (kp & 3) | (((kp >> 8) & 1) << 2) | (((kp >> 2) & 1) << 3) | (((kp >> 9) & 1) << 4);
        const int d = (kp >> 3) & 31;
        vals[e] = lin[lz * 1024 + c * CDIM + d];
      }
      const int dest = ((z >> 5) << 15) + (ks << 9) + (hh << 8) + ((z & 31) << 3);
      *(u32x4*)(w2T + dest) = *(const u32x4*)vals;
    }
  }
}

// ---------------- main: 8x8 (i,j) tiles = 64 pairs/block, 128x64 wave-tiles ----------------
__global__ __launch_bounds__(512, 2) void opm_main(
    const unsigned short* __restrict__ a_t, const unsigned short* __restrict__ b_t,
    const unsigned short* __restrict__ w2T, const float* __restrict__ bout,
    float* __restrict__ out)
{
  // staging: A0/A1/A2 [0,48K), B0/B1/B2 [48K,96K); O overlays [0,128K) after phase A
  __shared__ __align__(16) char smem[131072];
  char* o_sh = smem;

  const int tid = threadIdx.x;
  const int lane = tid & 63;
  const int wid = tid >> 6;           // 0..7
  const int l31 = lane & 31;
  const int h = lane >> 5;

  // 2-D XCD blocking over 1024 blocks: each XCD gets 8 it x 16 jt (1MB a + 2MB b + 0.25MB W2 < 4MB L2)
  const int bxr = blockIdx.x;
  const int xc = bxr & 7;
  const int q7 = bxr >> 3;            // 0..127
  const int it = (xc & 3) * 8 + (q7 >> 4);   // 0..31
  const int jt = (xc >> 2) * 16 + (q7 & 15); // 0..31
  const int i0 = it * IB;
  const int j0 = jt * JB;

  const int wm = wid >> 2;            // 0..1: M 128-row group
  const int wn = wid & 3;             // 0..3: N 64-row group
  const int wbase = wid * 1024;

  // acc[sub 0..3][ni 0..1]
  f32x16 acc00 = {}, acc01 = {}, acc10 = {}, acc11 = {};
  f32x16 acc20 = {}, acc21 = {}, acc30 = {}, acc31 = {};

  // chunk q (16B) at LDS offset q*16 holds global n-group gs = (q&3) ^ ((q>>3)&3)
  auto STAGE_A = [&](int buf, int nc) {
    const int nbase = nc * 32;
    char* A = smem + buf * 16384;
#pragma unroll
    for (int pass = 0; pass < 2; ++pass) {
      const int q = pass * 512 + tid;
      const int row = q >> 2;
      const int gs = (q & 3) ^ ((q >> 3) & 3);
      const unsigned short* src = a_t + ((i0 + (row >> 5)) * 32 + (row & 31)) * 256 + nbase + gs * 8;
      gload16(src, A + pass * 8192 + wbase);
    }
  };
  auto STAGE_B = [&](int buf, int nc) {
    const int nbase = nc * 32;
    char* B = smem + 49152 + buf * 16384;
#pragma unroll
    for (int pass = 0; pass < 2; ++pass) {
      const int q = pass * 512 + tid;
      const int row = q >> 2;
      const int gs = (q & 3) ^ ((q >> 3) & 3);
      const unsigned short* src = b_t + ((j0 + (row >> 5)) * 32 + (row & 31)) * 256 + nbase + gs * 8;
      gload16(src, B + pass * 8192 + wbase);
    }
  };

  // one K-half: 4 A-frags + 2 B-frags (ds_read_b128), 8 MFMA
  auto HALF = [&](int buf, int ks) {
    char* A = smem + buf * 16384;
    char* B = smem + 49152 + buf * 16384;
    const int s = ks * 2 + h;
    bfx8 af0, af1, af2, af3, bf0, bf1;
    { const int r = wm * 128 +  0 + l31; af0 = *(const bfx8*)(A + r * 64 + (((s ^ (r >> 1)) & 3) << 4)); }
    { const int r = wm * 128 + 32 + l31; af1 = *(const bfx8*)(A + r * 64 + (((s ^ (r >> 1)) & 3) << 4)); }
    { const int r = wm * 128 + 64 + l31; af2 = *(const bfx8*)(A + r * 64 + (((s ^ (r >> 1)) & 3) << 4)); }
    { const int r = wm * 128 + 96 + l31; af3 = *(const bfx8*)(A + r * 64 + (((s ^ (r >> 1)) & 3) << 4)); }
    { const int r = wn * 64 + l31;       bf0 = *(const bfx8*)(B + r * 64 + (((s ^ (r >> 1)) & 3) << 4)); }
    { const int r = wn * 64 + 32 + l31;  bf1 = *(const bfx8*)(B + r * 64 + (((s ^ (r >> 1)) & 3) << 4)); }
    __builtin_amdgcn_s_setprio(1);
    acc00 = __builtin_amdgcn_mfma_f32_32x32x16_bf16(af0, bf0, acc00, 0, 0, 0);
    acc01 = __builtin_amdgcn_mfma_f32_32x32x16_bf16(af0, bf1, acc01, 0, 0, 0);
    acc10 = __builtin_amdgcn_mfma_f32_32x32x16_bf16(af1, bf0, acc10, 0, 0, 0);
    acc11 = __builtin_amdgcn_mfma_f32_32x32x16_bf16(af1, bf1, acc11, 0, 0, 0);
    acc20 = __builtin_amdgcn_mfma_f32_32x32x16_bf16(af2, bf0, acc20, 0, 0, 0);
    acc21 = __builtin_amdgcn_mfma_f32_32x32x16_bf16(af2, bf1, acc21, 0, 0, 0);
    acc30 = __builtin_amdgcn_mfma_f32_32x32x16_bf16(af3, bf0, acc30, 0, 0, 0);
    acc31 = __builtin_amdgcn_mfma_f32_32x32x16_bf16(af3, bf1, acc31, 0, 0, 0);
    __builtin_amdgcn_s_setprio(0);
  };

  // prologue: chunks 0,1 fully in flight (8 loads/thread)
  STAGE_A(0, 0); STAGE_B(0, 0);
  STAGE_A(1, 1); STAGE_B(1, 1);

#pragma unroll
  for (int c = 0; c < 8; ++c) {
    const int buf = c % 3;
    // ---- P0: issue next A-stage, counted wait for chunk c, half 0
    if (c + 2 < 8) STAGE_A((c + 2) % 3, c + 2);
    if (c <= 5)      { asm volatile("s_waitcnt vmcnt(6)" ::: "memory"); }
    else if (c == 6) { asm volatile("s_waitcnt vmcnt(4)" ::: "memory"); }
    else             { asm volatile("s_waitcnt vmcnt(0)" ::: "memory"); }
    __builtin_amdgcn_s_barrier();
    asm volatile("" ::: "memory");
    HALF(buf, 0);
    asm volatile("s_waitcnt lgkmcnt(0)" ::: "memory");
    __builtin_amdgcn_s_barrier();
    // ---- P1: issue next B-stage, half 1
    if (c + 2 < 8) STAGE_B((c + 2) % 3, c + 2);
    asm volatile("" ::: "memory");
    HALF(buf, 1);
    asm volatile("s_waitcnt lgkmcnt(0)" ::: "memory");
    __builtin_amdgcn_s_barrier();
  }
  __syncthreads();   // drain before O overlays staging

  // ---- O -> LDS: pair p at [p*2048 + ((d + 32*c2 + 64*c4) ^ (p&7))*16], p = iloc*8 + jloc
  {
    const f32x16 av[8] = { acc00 * 0.00390625f, acc01 * 0.00390625f,
                           acc10 * 0.00390625f, acc11 * 0.00390625f,
                           acc20 * 0.00390625f, acc21 * 0.00390625f,
                           acc30 * 0.00390625f, acc31 * 0.00390625f };
#pragma unroll
    for (int sub = 0; sub < 4; ++sub) {
#pragma unroll
      for (int ni = 0; ni < 2; ++ni) {
        const f32x16 a = av[sub * 2 + ni];
        const int p = (wm * 4 + sub) * 8 + (wn * 2 + ni);
#pragma unroll
        for (int c4 = 0; c4 < 2; ++c4) {
          const int sl = l31 + 32 * h + 64 * c4;
          u32x4 v;
          v[0] = cvtpk(a[8 * c4 + 0], a[8 * c4 + 1]);
          v[1] = cvtpk(a[8 * c4 + 2], a[8 * c4 + 3]);
          v[2] = cvtpk(a[8 * c4 + 4], a[8 * c4 + 5]);
          v[3] = cvtpk(a[8 * c4 + 6], a[8 * c4 + 7]);
          *(u32x4*)(o_sh + p * 2048 + ((sl ^ (p & 7)) << 4)) = v;
        }
      }
    }
  }
  __syncthreads();

  // ---- phase B: waves (ztp 0-1, kh 0-3); pair-halves pg 0-1 share W2 fragments
  {
    const int ztp = wid & 1;
    const int kh = wid >> 1;
    const unsigned short* wpa = w2T + ((ztp * 2 + 0) << 15) + (h << 8) + (l31 << 3);
    const unsigned short* wpb = w2T + ((ztp * 2 + 1) << 15) + (h << 8) + (l31 << 3);
    const int p0 = l31;            // pg 0
    const int p1 = 32 + l31;       // pg 1
    const int ob0 = p0 * 2048, ox0 = p0 & 7;
    const int ob1 = p1 * 2048, ox1 = p1 & 7;
    const int ks0 = kh * 16;

    bfx8 wa[4], wb[4];
#pragma unroll
    for (int q = 0; q < 4; ++q) {
      wa[q] = *(const bfx8*)(wpa + ((ks0 + q) << 9));
      wb[q] = *(const bfx8*)(wpb + ((ks0 + q) << 9));
    }
    bfx8 oc0 = *(const bfx8*)(o_sh + ob0 + ((((ks0 << 1) + h) ^ ox0) << 4));
    bfx8 on0 = *(const bfx8*)(o_sh + ob0 + (((((ks0 + 1) << 1) + h) ^ ox0) << 4));
    bfx8 oc1 = *(const bfx8*)(o_sh + ob1 + ((((ks0 << 1) + h) ^ ox1) << 4));
    bfx8 on1 = *(const bfx8*)(o_sh + ob1 + (((((ks0 + 1) << 1) + h) ^ ox1) << 4));

    f32x16 za0 = {}, zb0 = {}, za1 = {}, zb1 = {};
#pragma unroll
    for (int st = 0; st < 16; ++st) {
      const int q = st & 3;
      __builtin_amdgcn_s_setprio(1);
      za0 = __builtin_amdgcn_mfma_f32_32x32x16_bf16(wa[q], oc0, za0, 0, 0, 0);
      zb0 = __builtin_amdgcn_mfma_f32_32x32x16_bf16(wb[q], oc0, zb0, 0, 0, 0);
      za1 = __builtin_amdgcn_mfma_f32_32x32x16_bf16(wa[q], oc1, za1, 0, 0, 0);
      zb1 = __builtin_amdgcn_mfma_f32_32x32x16_bf16(wb[q], oc1, zb1, 0, 0, 0);
      __builtin_amdgcn_s_setprio(0);
      oc0 = on0; oc1 = on1;
      if (st < 14) {
        const int sl = ((ks0 + st + 2) << 1) + h;
        on0 = *(const bfx8*)(o_sh + ob0 + ((sl ^ ox0) << 4));
        on1 = *(const bfx8*)(o_sh + ob1 + ((sl ^ ox1) << 4));
      }
      if (st < 12) {
        wa[q] = *(const bfx8*)(wpa + ((ks0 + st + 4) << 9));
        wb[q] = *(const bfx8*)(wpb + ((ks0 + st + 4) << 9));
      }
    }
    __syncthreads();   // all O reads done; o_sh reusable for partials

    // partials: [slot(4) 16KB][zs 8KB][(g2*2+h)][p(64)] fx4; stage2 at 65536 + ztp*16384
    const int slot = (kh >> 1) * 2 + ztp;
    auto PWRITE = [&](char* base) {
#pragma unroll
      for (int zs = 0; zs < 2; ++zs) {
        const f32x16& A0 = zs ? zb0 : za0;
        const f32x16& A1 = zs ? zb1 : za1;
#pragma unroll
        for (int g2 = 0; g2 < 4; ++g2) {
          fx4 v0 = { A0[4 * g2], A0[4 * g2 + 1], A0[4 * g2 + 2], A0[4 * g2 + 3] };
          fx4 v1 = { A1[4 * g2], A1[4 * g2 + 1], A1[4 * g2 + 2], A1[4 * g2 + 3] };
          *(fx4*)(base + zs * 8192 + (((g2 * 2 + h) * 64 + p0) << 4)) = v0;
          *(fx4*)(base + zs * 8192 + (((g2 * 2 + h) * 64 + p1) << 4)) = v1;
        }
      }
    };
    auto PADD = [&](const char* base) {
#pragma unroll
      for (int zs = 0; zs < 2; ++zs) {
        f32x16& A0 = zs ? zb0 : za0;
        f32x16& A1 = zs ? zb1 : za1;
#pragma unroll
        for (int g2 = 0; g2 < 4; ++g2) {
          const fx4 v0 = *(const fx4*)(base + zs * 8192 + (((g2 * 2 + h) * 64 + p0) << 4));
          const fx4 v1 = *(const fx4*)(base + zs * 8192 + (((g2 * 2 + h) * 64 + p1) << 4));
          A0[4 * g2 + 0] += v0[0]; A0[4 * g2 + 1] += v0[1];
          A0[4 * g2 + 2] += v0[2]; A0[4 * g2 + 3] += v0[3];
          A1[4 * g2 + 0] += v1[0]; A1[4 * g2 + 1] += v1[1];
          A1[4 * g2 + 2] += v1[2]; A1[4 * g2 + 3] += v1[3];
        }
      }
    };
    if (kh & 1) PWRITE(o_sh + slot * 16384);
    __syncthreads();
    if (!(kh & 1)) {
      PADD(o_sh + slot * 16384);
      if (kh == 2) PWRITE(o_sh + 65536 + ztp * 16384);
    }
    __syncthreads();
    if (kh == 0) {
      PADD(o_sh + 65536 + ztp * 16384);
      const float* bp = bout + ztp * 64;
#pragma unroll
      for (int pg = 0; pg < 2; ++pg) {
        const int p = pg * 32 + l31;
        const int i = i0 + (p >> 3), j = j0 + (p & 7);
        float* op = out + (i * SDIM + j) * CZ + ztp * 64;
#pragma unroll
        for (int zs = 0; zs < 2; ++zs) {
          const f32x16& A = zs ? (pg ? zb1 : zb0) : (pg ? za1 : za0);
#pragma unroll
          for (int g2 = 0; g2 < 4; ++g2) {
            const int zl = zs * 32 + g2 * 8 + h * 4;
            fx4 v = { A[4 * g2], A[4 * g2 + 1], A[4 * g2 + 2], A[4 * g2 + 3] };
            v += *(const fx4*)(bp + zl);
            *(fx4*)(op + zl) = v;
          }
        }
      }
    }
  }
}

extern "C" void kernel_launch(void* const* d_in, const int* in_sizes, int n_in,
                              void* d_out, int out_size, void* d_ws, size_t ws_size,
                              hipStream_t stream) {
  const float* m_si  = (const float*)d_in[0];
  const float* gamma = (const float*)d_in[1];
  const float* beta  = (const float*)d_in[2];
  const float* Wab   = (const float*)d_in[3];
  const float* Wout  = (const float*)d_in[4];
  const float* bout  = (const float*)d_in[5];
  float* out = (float*)d_out;

  char* ws = (char*)d_ws;
  unsigned short* a_t = (unsigned short*)ws;                    // 4 MB
  unsigned short* b_t = (unsigned short*)(ws + (4u << 20));     // 4 MB
  unsigned short* w2T = (unsigned short*)(ws + (8u << 20));     // 256 KB

  opm_prep<<<dim3(SDIM + 32), dim3(256), 0, stream>>>(m_si, gamma, beta, Wab, Wout, a_t, b_t, w2T);
  opm_main<<<dim3(1024), dim3(512), 0, stream>>>(a_t, b_t, w2T, bout, out);
}